// Round 3
// baseline (320.966 us; speedup 1.0000x reference)
//
#include <hip/hip_runtime.h>
#include <hip/hip_bf16.h>
#include <stdint.h>

typedef short short8 __attribute__((ext_vector_type(8)));
typedef float f32x16 __attribute__((ext_vector_type(16)));

#define KD 8192
#define NT 128   // K-tiles of 64 (8 features per tile)

__device__ __forceinline__ unsigned short bfb(float f) {
    __hip_bfloat16 h = __float2bfloat16(f);
    return __builtin_bit_cast(unsigned short, h);
}

// A-fragment = 8 Chebyshev channels of one (row, feature): [x, tanh, T2..T7]
__device__ __forceinline__ short8 cheby8(float xv) {
    float e  = __builtin_amdgcn_exp2f(xv * 2.8853900817779268f); // exp(2x)
    float xn = 1.0f - 2.0f * __builtin_amdgcn_rcpf(1.0f + e);    // tanh(x)
    float x2 = xn + xn;
    float t2 = x2 * xn - 1.0f;
    float t3 = x2 * t2 - xn;
    float t4 = x2 * t3 - t2;
    float t5 = x2 * t4 - t3;
    float t6 = x2 * t5 - t4;
    float t7 = x2 * t6 - t5;
    short8 v;
    v[0] = bfb(xv); v[1] = bfb(xn); v[2] = bfb(t2); v[3] = bfb(t3);
    v[4] = bfb(t4); v[5] = bfb(t5); v[6] = bfb(t6); v[7] = bfb(t7);
    return v;
}

// Build W'[o, i*8+c] bf16: c==0 -> base_weight[o,i], c=1..7 -> C[o,i,c]
__global__ void prep_w(const float* __restrict__ C, const float* __restrict__ W,
                       unsigned short* __restrict__ Bw) {
    int g = blockIdx.x * 256 + threadIdx.x;
    int o = g >> 10, i = g & 1023;
    const float* src = C + ((size_t)o * 8192 + i * 8);
    float4 v0 = *(const float4*)src;
    float4 v1 = *(const float4*)(src + 4);
    v0.x = W[o * 1024 + i];
    short8 r;
    r[0] = bfb(v0.x); r[1] = bfb(v0.y); r[2] = bfb(v0.z); r[3] = bfb(v0.w);
    r[4] = bfb(v1.x); r[5] = bfb(v1.y); r[6] = bfb(v1.z); r[7] = bfb(v1.w);
    *(short8*)(Bw + (size_t)g * 8) = r;
}

// bias[o] = sum_i C[o,i,0]
__global__ void prep_bias(const float* __restrict__ C, float* __restrict__ bias) {
    int o = blockIdx.x;
    int tid = threadIdx.x;
    float s = 0.f;
    for (int i = tid; i < 1024; i += 256)
        s += C[(size_t)o * 8192 + (size_t)i * 8];
    #pragma unroll
    for (int off = 32; off > 0; off >>= 1) s += __shfl_down(s, off);
    __shared__ float red[4];
    if ((tid & 63) == 0) red[tid >> 6] = s;
    __syncthreads();
    if (tid == 0) bias[o] = red[0] + red[1] + red[2] + red[3];
}

// -------- 256x256xBK64 GEMM, A computed in-register per lane, 32x32x16 MFMA --------

#define GLDS(NXT_, C_, TT_) \
    __builtin_amdgcn_global_load_lds( \
        (const __attribute__((address_space(1))) unsigned int*)((const char*)Bw + boff[C_] + (size_t)(TT_) * 128), \
        (__attribute__((address_space(3))) unsigned int*)(&Bs[NXT_][(wave * 4 + (C_)) * 8][0]), 16, 0, 0)

#define PHASE(CUR_, KK_) { \
    const int fb_ = (KK_) * 2 + lg;  /* feature slot 0..7; lane's k-group */ \
    float xv0_ = Xs[CUR_][fb_][wm + lr]; \
    float xv1_ = Xs[CUR_][fb_][wm + 32 + lr]; \
    float xv2_ = Xs[CUR_][fb_][wm + 64 + lr]; \
    float xv3_ = Xs[CUR_][fb_][wm + 96 + lr]; \
    const int row0_ = wn + lr, row1_ = wn + 32 + lr; \
    short8 b0_ = *(const short8*)((const char*)&Bs[CUR_][0][0] + row0_ * 128 + ((fb_ ^ (row0_ & 7)) * 16)); \
    short8 b1_ = *(const short8*)((const char*)&Bs[CUR_][0][0] + row1_ * 128 + ((fb_ ^ (row1_ & 7)) * 16)); \
    short8 a0_ = cheby8(xv0_); \
    short8 a1_ = cheby8(xv1_); \
    short8 a2_ = cheby8(xv2_); \
    short8 a3_ = cheby8(xv3_); \
    __builtin_amdgcn_s_setprio(1); \
    acc[0][0] = __builtin_amdgcn_mfma_f32_32x32x16_bf16(a0_, b0_, acc[0][0], 0, 0, 0); \
    acc[0][1] = __builtin_amdgcn_mfma_f32_32x32x16_bf16(a0_, b1_, acc[0][1], 0, 0, 0); \
    acc[1][0] = __builtin_amdgcn_mfma_f32_32x32x16_bf16(a1_, b0_, acc[1][0], 0, 0, 0); \
    acc[1][1] = __builtin_amdgcn_mfma_f32_32x32x16_bf16(a1_, b1_, acc[1][1], 0, 0, 0); \
    acc[2][0] = __builtin_amdgcn_mfma_f32_32x32x16_bf16(a2_, b0_, acc[2][0], 0, 0, 0); \
    acc[2][1] = __builtin_amdgcn_mfma_f32_32x32x16_bf16(a2_, b1_, acc[2][1], 0, 0, 0); \
    acc[3][0] = __builtin_amdgcn_mfma_f32_32x32x16_bf16(a3_, b0_, acc[3][0], 0, 0, 0); \
    acc[3][1] = __builtin_amdgcn_mfma_f32_32x32x16_bf16(a3_, b1_, acc[3][1], 0, 0, 0); \
    __builtin_amdgcn_s_setprio(0); \
}

#define TILE(CUR_, NXT_, T_) { \
    const int tn_ = ((T_) + 1 < NT) ? (T_) + 1 : NT - 1; \
    float4 xr_ = *(const float4*)(xbase + (size_t)tn_ * 8);  /* next-tile x, in flight */ \
    GLDS(NXT_, 0, tn_); GLDS(NXT_, 1, tn_); GLDS(NXT_, 2, tn_); GLDS(NXT_, 3, tn_); \
    PHASE(CUR_, 0) \
    PHASE(CUR_, 1) \
    Xs[NXT_][xf + 0][arow] = xr_.x; \
    Xs[NXT_][xf + 1][arow] = xr_.y; \
    Xs[NXT_][xf + 2][arow] = xr_.z; \
    Xs[NXT_][xf + 3][arow] = xr_.w; \
    PHASE(CUR_, 2) \
    PHASE(CUR_, 3) \
    __syncthreads(); \
}

__global__ __launch_bounds__(512, 2)
void cheby_gemm(const float* __restrict__ X, const unsigned short* __restrict__ Bw,
                const float* __restrict__ bias, float* __restrict__ Out) {
    __shared__ unsigned short Bs[2][256][64];  // 64 KiB, XOR-swizzled (chunk ^= row&7)
    __shared__ float Xs[2][8][256];            // 16 KiB raw x, [feature][row]

    const int tid  = threadIdx.x;
    const int lane = tid & 63;
    const int wave = tid >> 6;

    // XCD-bijective swizzle: 256 blocks; 2 XCDs share one n-tile (4MB B slice -> L2)
    int bid = blockIdx.x;
    int lin = (bid & 7) * 32 + (bid >> 3);
    const int m0 = (lin & 63) << 8;
    const int n0 = (lin >> 6) << 8;

    const int wm = (wave >> 2) * 128;   // 2 M-waves x 4 N-waves; per-wave out 128x64
    const int wn = (wave & 3) * 64;
    const int lr = lane & 31;
    const int lg = lane >> 5;

    // x staging mapping: thread -> (row, 4 features)
    const int arow = tid >> 1;
    const int xf   = (tid & 1) * 4;
    const float* xbase = X + (size_t)(m0 + arow) * 1024 + xf;

    // B glds per-lane pre-swizzled source offsets (chunk ^= row&7)
    unsigned int boff[4];
    #pragma unroll
    for (int c = 0; c < 4; ++c) {
        int row   = (wave * 4 + c) * 8 + (lane >> 3);
        int chunk = (lane & 7) ^ (lane >> 3);
        boff[c] = ((unsigned)(n0 + row) * 8192u + (unsigned)chunk * 8u) * 2u;
    }

    f32x16 acc[4][2] = {};

    // ---- prologue: stage tile 0 ----
    {
        float4 xr_ = *(const float4*)(xbase);
        GLDS(0, 0, 0); GLDS(0, 1, 0); GLDS(0, 2, 0); GLDS(0, 3, 0);
        Xs[0][xf + 0][arow] = xr_.x;
        Xs[0][xf + 1][arow] = xr_.y;
        Xs[0][xf + 2][arow] = xr_.z;
        Xs[0][xf + 3][arow] = xr_.w;
        __syncthreads();
    }

    for (int t = 0; t < NT; t += 2) {
        TILE(0, 1, t)
        TILE(1, 0, t + 1)
    }

    // ---- epilogue: 32x32 C/D layout col=lane&31, row=(r&3)+8*(r>>2)+4*lg ----
    #pragma unroll
    for (int ni = 0; ni < 2; ++ni) {
        int col = n0 + wn + ni * 32 + lr;
        float bv = bias[col];
        #pragma unroll
        for (int mi = 0; mi < 4; ++mi) {
            #pragma unroll
            for (int r = 0; r < 16; ++r) {
                int row = m0 + wm + mi * 32 + 4 * lg + (r & 3) + 8 * (r >> 2);
                Out[(size_t)row * 1024 + col] = acc[mi][ni][r] + bv;
            }
        }
    }
}

extern "C" void kernel_launch(void* const* d_in, const int* in_sizes, int n_in,
                              void* d_out, int out_size, void* d_ws, size_t ws_size,
                              hipStream_t stream) {
    const float* x = (const float*)d_in[0];          // [16384,1024] f32
    const float* C = (const float*)d_in[1];          // [1024,1024,8] f32
    const float* W = (const float*)d_in[2];          // [1024,1024] f32
    float* out = (float*)d_out;                      // [16384,1024] f32

    unsigned short* Bw = (unsigned short*)d_ws;                          // 16 MB bf16 W'
    float* bias = (float*)((char*)d_ws + (size_t)16 * 1024 * 1024);      // 4 KB

    prep_w<<<4096, 256, 0, stream>>>(C, W, Bw);
    prep_bias<<<1024, 256, 0, stream>>>(C, bias);
    cheby_gemm<<<256, 512, 0, stream>>>(x, Bw, bias, out);
}

// Round 4
// 282.835 us; speedup vs baseline: 1.1348x; 1.1348x over previous
//
#include <hip/hip_runtime.h>
#include <hip/hip_bf16.h>
#include <stdint.h>

typedef short short8 __attribute__((ext_vector_type(8)));
typedef float f32x16 __attribute__((ext_vector_type(16)));

#define KD 8192
#define NT 128   // K-tiles of 64 (8 features per tile)

__device__ __forceinline__ unsigned short bfb(float f) {
    __hip_bfloat16 h = __float2bfloat16(f);
    return __builtin_bit_cast(unsigned short, h);
}

// A-fragment = 8 Chebyshev channels of one (row, feature): [x, tanh, T2..T7]
__device__ __forceinline__ short8 cheby8(float xv) {
    float e  = __builtin_amdgcn_exp2f(xv * 2.8853900817779268f); // exp(2x)
    float xn = 1.0f - 2.0f * __builtin_amdgcn_rcpf(1.0f + e);    // tanh(x)
    float x2 = xn + xn;
    float t2 = x2 * xn - 1.0f;
    float t3 = x2 * t2 - xn;
    float t4 = x2 * t3 - t2;
    float t5 = x2 * t4 - t3;
    float t6 = x2 * t5 - t4;
    float t7 = x2 * t6 - t5;
    short8 v;
    v[0] = bfb(xv); v[1] = bfb(xn); v[2] = bfb(t2); v[3] = bfb(t3);
    v[4] = bfb(t4); v[5] = bfb(t5); v[6] = bfb(t6); v[7] = bfb(t7);
    return v;
}

// Build W'[o, i*8+c] bf16: c==0 -> base_weight[o,i], c=1..7 -> C[o,i,c]
__global__ void prep_w(const float* __restrict__ C, const float* __restrict__ W,
                       unsigned short* __restrict__ Bw) {
    int g = blockIdx.x * 256 + threadIdx.x;
    int o = g >> 10, i = g & 1023;
    const float* src = C + ((size_t)o * 8192 + i * 8);
    float4 v0 = *(const float4*)src;
    float4 v1 = *(const float4*)(src + 4);
    v0.x = W[o * 1024 + i];
    short8 r;
    r[0] = bfb(v0.x); r[1] = bfb(v0.y); r[2] = bfb(v0.z); r[3] = bfb(v0.w);
    r[4] = bfb(v1.x); r[5] = bfb(v1.y); r[6] = bfb(v1.z); r[7] = bfb(v1.w);
    *(short8*)(Bw + (size_t)g * 8) = r;
}

// bias[o] = sum_i C[o,i,0]
__global__ void prep_bias(const float* __restrict__ C, float* __restrict__ bias) {
    int o = blockIdx.x;
    int tid = threadIdx.x;
    float s = 0.f;
    for (int i = tid; i < 1024; i += 256)
        s += C[(size_t)o * 8192 + (size_t)i * 8];
    #pragma unroll
    for (int off = 32; off > 0; off >>= 1) s += __shfl_down(s, off);
    __shared__ float red[4];
    if ((tid & 63) == 0) red[tid >> 6] = s;
    __syncthreads();
    if (tid == 0) bias[o] = red[0] + red[1] + red[2] + red[3];
}

// -------- 256x256xBK64 GEMM, 4Mx2N waves, in-register A, counted-vmcnt pipeline --------

#define GLDS(NXT_, C_, TT_) \
    __builtin_amdgcn_global_load_lds( \
        (const __attribute__((address_space(1))) unsigned int*)((const char*)Bw + boff[C_] + (size_t)(TT_) * 128), \
        (__attribute__((address_space(3))) unsigned int*)(&Bs[NXT_][(wave * 4 + (C_)) * 8][0]), 16, 0, 0)

#define XLOAD(DST_, TI_) { \
    const float* ap_ = xbase + (size_t)(TI_) * 8; \
    asm volatile("global_load_dwordx4 %0, %1, off" : "=&v"(DST_) : "v"(ap_)); }

#define PHASE(CUR_, KK_) { \
    const int fb_ = (KK_) * 2 + lg; \
    const int co_ = (fb_ ^ (lr & 7)) * 16; \
    float xv0_ = Xs[CUR_][fb_][wm + lr]; \
    float xv1_ = Xs[CUR_][fb_][wm + 32 + lr]; \
    short8 b0_ = *(const short8*)((const char*)&Bs[CUR_][0][0] + (wn +  0 + lr) * 128 + co_); \
    short8 b1_ = *(const short8*)((const char*)&Bs[CUR_][0][0] + (wn + 32 + lr) * 128 + co_); \
    short8 b2_ = *(const short8*)((const char*)&Bs[CUR_][0][0] + (wn + 64 + lr) * 128 + co_); \
    short8 b3_ = *(const short8*)((const char*)&Bs[CUR_][0][0] + (wn + 96 + lr) * 128 + co_); \
    short8 a0_ = cheby8(xv0_); \
    short8 a1_ = cheby8(xv1_); \
    __builtin_amdgcn_s_setprio(1); \
    acc[0][0] = __builtin_amdgcn_mfma_f32_32x32x16_bf16(a0_, b0_, acc[0][0], 0, 0, 0); \
    acc[0][1] = __builtin_amdgcn_mfma_f32_32x32x16_bf16(a0_, b1_, acc[0][1], 0, 0, 0); \
    acc[0][2] = __builtin_amdgcn_mfma_f32_32x32x16_bf16(a0_, b2_, acc[0][2], 0, 0, 0); \
    acc[0][3] = __builtin_amdgcn_mfma_f32_32x32x16_bf16(a0_, b3_, acc[0][3], 0, 0, 0); \
    acc[1][0] = __builtin_amdgcn_mfma_f32_32x32x16_bf16(a1_, b0_, acc[1][0], 0, 0, 0); \
    acc[1][1] = __builtin_amdgcn_mfma_f32_32x32x16_bf16(a1_, b1_, acc[1][1], 0, 0, 0); \
    acc[1][2] = __builtin_amdgcn_mfma_f32_32x32x16_bf16(a1_, b2_, acc[1][2], 0, 0, 0); \
    acc[1][3] = __builtin_amdgcn_mfma_f32_32x32x16_bf16(a1_, b3_, acc[1][3], 0, 0, 0); \
    __builtin_amdgcn_s_setprio(0); \
}

#define TILE(CUR_, NXT_, T_) { \
    const int tn_ = ((T_) + 1 < NT) ? (T_) + 1 : NT - 1; \
    float4 xr_; \
    XLOAD(xr_, tn_) \
    GLDS(NXT_, 0, tn_); GLDS(NXT_, 1, tn_); GLDS(NXT_, 2, tn_); GLDS(NXT_, 3, tn_); \
    asm volatile("s_waitcnt vmcnt(5)" ::: "memory"); /* B(t) landed; x+4 glds stay in flight */ \
    __builtin_amdgcn_sched_barrier(0); \
    __builtin_amdgcn_s_barrier(); \
    PHASE(CUR_, 0) \
    PHASE(CUR_, 1) \
    PHASE(CUR_, 2) \
    PHASE(CUR_, 3) \
    asm volatile("s_waitcnt vmcnt(4)" ::: "memory"); /* x(t+1) arrived; glds(t+1) in flight */ \
    __builtin_amdgcn_sched_barrier(0); \
    Xs[NXT_][xf + 0][arow] = xr_.x; \
    Xs[NXT_][xf + 1][arow] = xr_.y; \
    Xs[NXT_][xf + 2][arow] = xr_.z; \
    Xs[NXT_][xf + 3][arow] = xr_.w; \
    asm volatile("s_waitcnt lgkmcnt(0)" ::: "memory"); \
    __builtin_amdgcn_sched_barrier(0); \
    __builtin_amdgcn_s_barrier(); \
}

__global__ __launch_bounds__(512, 2)
void cheby_gemm(const float* __restrict__ X, const unsigned short* __restrict__ Bw,
                const float* __restrict__ bias, float* __restrict__ Out) {
    __shared__ unsigned short Bs[2][256][64];  // 64 KiB, XOR-swizzled (chunk ^= row&7)
    __shared__ float Xs[2][8][256];            // 16 KiB raw x, [feature][row]

    const int tid  = threadIdx.x;
    const int lane = tid & 63;
    const int wave = tid >> 6;

    // XCD-bijective swizzle: per XCD all 32 blocks share one 4MB B n-slice (L2-resident)
    int bid = blockIdx.x;
    int lin = (bid & 7) * 32 + (bid >> 3);
    const int m0 = (lin & 63) << 8;
    const int n0 = (lin >> 6) << 8;

    const int wm = (wave >> 1) * 64;    // 4 M-waves x 2 N-waves; per-wave out 64x128
    const int wn = (wave & 1) * 128;
    const int lr = lane & 31;
    const int lg = lane >> 5;

    // x staging mapping: thread -> (row, 4 features)
    const int arow = tid >> 1;
    const int xf   = (tid & 1) * 4;
    const float* xbase = X + (size_t)(m0 + arow) * 1024 + xf;

    // B glds per-lane pre-swizzled source offsets (chunk ^= row&7)
    unsigned int boff[4];
    #pragma unroll
    for (int c = 0; c < 4; ++c) {
        int row   = (wave * 4 + c) * 8 + (lane >> 3);
        int chunk = (lane & 7) ^ (lane >> 3);
        boff[c] = ((unsigned)(n0 + row) * 8192u + (unsigned)chunk * 8u) * 2u;
    }

    f32x16 acc[2][4] = {};

    // ---- prologue: stage tile 0; leave glds(0) in flight (4 outstanding) ----
    {
        float4 xr_;
        XLOAD(xr_, 0)
        GLDS(0, 0, 0); GLDS(0, 1, 0); GLDS(0, 2, 0); GLDS(0, 3, 0);
        asm volatile("s_waitcnt vmcnt(4)" ::: "memory");  // x(0) done
        __builtin_amdgcn_sched_barrier(0);
        Xs[0][xf + 0][arow] = xr_.x;
        Xs[0][xf + 1][arow] = xr_.y;
        Xs[0][xf + 2][arow] = xr_.z;
        Xs[0][xf + 3][arow] = xr_.w;
        asm volatile("s_waitcnt lgkmcnt(0)" ::: "memory");
        __builtin_amdgcn_sched_barrier(0);
        __builtin_amdgcn_s_barrier();
    }

    for (int t = 0; t < NT; t += 2) {
        TILE(0, 1, t)
        TILE(1, 0, t + 1)
    }

    // ---- epilogue: 32x32 C/D layout col=lane&31, row=(r&3)+8*(r>>2)+4*lg ----
    #pragma unroll
    for (int ni = 0; ni < 4; ++ni) {
        int col = n0 + wn + ni * 32 + lr;
        float bv = bias[col];
        #pragma unroll
        for (int mi = 0; mi < 2; ++mi) {
            #pragma unroll
            for (int r = 0; r < 16; ++r) {
                int row = m0 + wm + mi * 32 + 4 * lg + (r & 3) + 8 * (r >> 2);
                Out[(size_t)row * 1024 + col] = acc[mi][ni][r] + bv;
            }
        }
    }
}

extern "C" void kernel_launch(void* const* d_in, const int* in_sizes, int n_in,
                              void* d_out, int out_size, void* d_ws, size_t ws_size,
                              hipStream_t stream) {
    const float* x = (const float*)d_in[0];          // [16384,1024] f32
    const float* C = (const float*)d_in[1];          // [1024,1024,8] f32
    const float* W = (const float*)d_in[2];          // [1024,1024] f32
    float* out = (float*)d_out;                      // [16384,1024] f32

    unsigned short* Bw = (unsigned short*)d_ws;                          // 16 MB bf16 W'
    float* bias = (float*)((char*)d_ws + (size_t)16 * 1024 * 1024);      // 4 KB

    prep_w<<<4096, 256, 0, stream>>>(C, W, Bw);
    prep_bias<<<1024, 256, 0, stream>>>(C, bias);
    cheby_gemm<<<256, 512, 0, stream>>>(x, Bw, bias, out);
}